// Round 1
// baseline (202.776 us; speedup 1.0000x reference)
//
#include <hip/hip_runtime.h>
#include <stdint.h>

// ---------------- types / helpers ----------------
typedef __attribute__((ext_vector_type(8))) short bf16x8;
typedef __attribute__((ext_vector_type(4))) short bf16x4;
typedef __attribute__((ext_vector_type(4))) float f32x4;

#define DEV static __device__ __forceinline__

DEV float bf2f(short s) {
    unsigned u = ((unsigned)(unsigned short)s) << 16;
    return __builtin_bit_cast(float, u);
}
DEV short f2bf(float f) {  // RNE
    unsigned u = __builtin_bit_cast(unsigned, f);
    unsigned r = u + 0x7fffu + ((u >> 16) & 1u);
    return (short)(r >> 16);
}

// problem constants
#define NCH 256
#define HH  64
#define WW  64
#define CMd 64
#define PTOT 32768
#define NEXP2 (-2.885390081777927f)   // -2*log2(e)

// ws byte offsets
#define WS_WC1B 0
#define WS_WC2B 32768
#define WS_WD1R 65536
#define WS_WR   360448
#define WS_EKT  1540096
#define WS_EN   2719744

// ---------------- prep: weight reorder + bf16 cast ----------------
// Wr  [256][2304] : Wr[o][k*256+n]   = W[o][n][k]
// wd1r[ 64][2304] : wd1r[m][k*256+n] = w_d1[m][n][kh][kw], k=kh*3+kw
// wc1b[ 64][256]  : = w_c1 (bf16)
// wc2b[256][ 64]  : = w_c2 (bf16)
__global__ __launch_bounds__(256) void k_prep(const float* __restrict__ W, const float* __restrict__ w_d1,
                                              const float* __restrict__ w_c1, const float* __restrict__ w_c2,
                                              short* __restrict__ Wr, short* __restrict__ wd1r,
                                              short* __restrict__ wc1b, short* __restrict__ wc2b) {
    int t = blockIdx.x * 256 + threadIdx.x;
    if (t < 589824) {
        int o = t / 2304, rr = t - o * 2304;
        int k = rr >> 8, n = rr & 255;
        Wr[t] = f2bf(W[o * 2304 + n * 9 + k]);
    } else if (t < 589824 + 147456) {
        int t2 = t - 589824;
        int m = t2 / 2304, rr = t2 - m * 2304;
        int k = rr >> 8, n = rr & 255;
        wd1r[t2] = f2bf(w_d1[m * 2304 + n * 9 + k]);
    } else if (t < 589824 + 147456 + 16384) {
        int t3 = t - (589824 + 147456);
        wc1b[t3] = f2bf(w_c1[t3]);
    } else if (t < 589824 + 147456 + 32768) {
        int t4 = t - (589824 + 147456 + 16384);
        wc2b[t4] = f2bf(w_c2[t4]);
    }
}

// ---------------- shared x staging ----------------
// xs LDS layout: [3][66][264] bf16; (r,c,ch): r=row h-1..h+1, c=w+1 (c=0,65 zero pads), ch channel.
// row stride 264*2=528B (16B aligned); elem (r,c,ch) at ((r*66+c)*264+ch).
DEV void stage_xs(short* xs, const float* __restrict__ x, int b, int h, float scale) {
    const int tid = threadIdx.x;  // 512 threads
    // zero pad columns c=0 and c=65
    for (int i = tid; i < 3 * 2 * NCH; i += 512) {
        int r = i >> 9, rem = i & 511;
        int cc = (rem >> 8) ? 65 : 0, ch = rem & 255;
        xs[(r * 66 + cc) * 264 + ch] = 0;
    }
    const int lane16 = tid & 15;
    const int chb = tid >> 4;  // 0..31
    for (int r = 0; r < 3; ++r) {
        int hr = h + r - 1;
        if (hr < 0 || hr >= HH) {
            for (int i = tid; i < NCH * WW; i += 512) {
                int ch = i >> 6, w = i & 63;
                xs[(r * 66 + (w + 1)) * 264 + ch] = 0;
            }
        } else {
            for (int pass = 0; pass < 8; ++pass) {
                int ch = pass * 32 + chb;
                const f32x4 v = *(const f32x4*)(x + (((size_t)(b * NCH + ch) * HH + hr) << 6) + lane16 * 4);
                int cb = lane16 * 4 + 1;
                xs[(r * 66 + cb + 0) * 264 + ch] = f2bf(v[0] * scale);
                xs[(r * 66 + cb + 1) * 264 + ch] = f2bf(v[1] * scale);
                xs[(r * 66 + cb + 2) * 264 + ch] = f2bf(v[2] * scale);
                xs[(r * 66 + cb + 3) * 264 + ch] = f2bf(v[3] * scale);
            }
        }
    }
}

// ---------------- branch kernel: en (= e^{-2c}) and ekT (= e^{-2d}) ----------------
#define BR_CHUNK 104544                  // [64][40] bf16 = 5120
#define BR_YC   (BR_CHUNK + 5120)        // [64][72] bf16 = 9216
#define BR_WC2  (BR_YC + 9216)           // [256][72] bf16 = 36864 ; reused as yd [64][68] f32
#define BR_TOTAL (BR_WC2 + 36864)        // 155744 B

__global__ __launch_bounds__(512, 1) void k_branch(const float* __restrict__ x,
        const float* __restrict__ b_c1, const float* __restrict__ b_c2,
        const float* __restrict__ b_d1, const float* __restrict__ w_d2, const float* __restrict__ b_d2,
        const short* __restrict__ wc1b, const short* __restrict__ wc2b, const short* __restrict__ wd1r,
        short* __restrict__ en, float* __restrict__ ekT) {
    extern __shared__ char smem[];
    short* xs    = (short*)(smem);
    short* chunk = (short*)(smem + BR_CHUNK);
    short* yc    = (short*)(smem + BR_YC);
    short* wc2l  = (short*)(smem + BR_WC2);
    float* ydl   = (float*)(smem + BR_WC2);

    const int rw = blockIdx.x;
    const int b = rw >> 6, h = rw & 63;
    const int p0 = rw << 6;
    const int tid = threadIdx.x;
    const int lane = tid & 63, wave = tid >> 6;
    const int l16 = lane & 15, lg = lane >> 4;
    const int wn = wave & 3, wm = wave >> 2;  // 2 (M) x 4 (N) wave grid

    stage_xs(xs, x, b, h, 1.0f);
    {   // stage full wc2b (256x64) -> wc2l [256][72]
        int row = tid >> 1, seg = tid & 1;
        const short* src = wc2b + row * 64 + seg * 32;
        short* dst = wc2l + row * 72 + seg * 32;
        *(bf16x8*)(dst + 0)  = *(const bf16x8*)(src + 0);
        *(bf16x8*)(dst + 8)  = *(const bf16x8*)(src + 8);
        *(bf16x8*)(dst + 16) = *(const bf16x8*)(src + 16);
        *(bf16x8*)(dst + 24) = *(const bf16x8*)(src + 24);
    }
    __syncthreads();

    const int crow = tid >> 3, cc4 = (tid & 7) << 2;  // chunk staging map

    // ---- chan GEMM1: yc[64px][64cm] = relu(x . w_c1^T + b_c1)
    {
        f32x4 acc[2] = {};
        bf16x4 pref = *(const bf16x4*)(wc1b + crow * 256 + cc4);
        for (int s = 0; s < 8; ++s) {
            bf16x4 curv = pref;
            if (s < 7) pref = *(const bf16x4*)(wc1b + crow * 256 + (s + 1) * 32 + cc4);
            *(bf16x4*)(chunk + crow * 40 + cc4) = curv;
            __syncthreads();
            int n0 = s * 32;
            bf16x8 bfr = *(const bf16x8*)(chunk + (wn * 16 + l16) * 40 + lg * 8);
            #pragma unroll
            for (int mt = 0; mt < 2; ++mt) {
                int px = wm * 32 + mt * 16 + l16;
                bf16x8 afr = *(const bf16x8*)(xs + (66 + px + 1) * 264 + n0 + lg * 8);
                acc[mt] = __builtin_amdgcn_mfma_f32_16x16x32_bf16(afr, bfr, acc[mt], 0, 0, 0);
            }
            __syncthreads();
        }
        int cm = wn * 16 + l16;
        float bias = b_c1[cm];
        #pragma unroll
        for (int mt = 0; mt < 2; ++mt)
            #pragma unroll
            for (int r = 0; r < 4; ++r) {
                int px = wm * 32 + mt * 16 + lg * 4 + r;
                float v = acc[mt][r] + bias;
                yc[px * 72 + cm] = f2bf(v > 0.f ? v : 0.f);
            }
    }
    __syncthreads();

    // ---- chan GEMM2: c[64px][256] = yc . w_c2^T + b_c2 ; en = exp(-2c)
    {
        f32x4 acc[2][4] = {};
        #pragma unroll
        for (int s = 0; s < 2; ++s) {
            int k0 = s * 32;
            bf16x8 afr[2], bfr[4];
            #pragma unroll
            for (int mt = 0; mt < 2; ++mt)
                afr[mt] = *(const bf16x8*)(yc + (wm * 32 + mt * 16 + l16) * 72 + k0 + lg * 8);
            #pragma unroll
            for (int nt = 0; nt < 4; ++nt)
                bfr[nt] = *(const bf16x8*)(wc2l + (wn * 64 + nt * 16 + l16) * 72 + k0 + lg * 8);
            #pragma unroll
            for (int mt = 0; mt < 2; ++mt)
                #pragma unroll
                for (int nt = 0; nt < 4; ++nt)
                    acc[mt][nt] = __builtin_amdgcn_mfma_f32_16x16x32_bf16(afr[mt], bfr[nt], acc[mt][nt], 0, 0, 0);
        }
        #pragma unroll
        for (int nt = 0; nt < 4; ++nt) {
            int nc = wn * 64 + nt * 16 + l16;
            float bias = b_c2[nc];
            #pragma unroll
            for (int mt = 0; mt < 2; ++mt)
                #pragma unroll
                for (int r = 0; r < 4; ++r) {
                    int px = wm * 32 + mt * 16 + lg * 4 + r;
                    float cv = acc[mt][nt][r] + bias;
                    en[(size_t)(p0 + px) * 256 + nc] = f2bf(exp2f(NEXP2 * cv));
                }
        }
    }
    __syncthreads();

    // ---- conv GEMM: yd[64px][64cm] = relu(conv3x3(x,w_d1) + b_d1)
    {
        f32x4 acc[2] = {};
        bf16x4 pref = *(const bf16x4*)(wd1r + crow * 2304 + cc4);
        for (int kc = 0; kc < 72; ++kc) {
            bf16x4 curv = pref;
            if (kc < 71) pref = *(const bf16x4*)(wd1r + crow * 2304 + (kc + 1) * 32 + cc4);
            *(bf16x4*)(chunk + crow * 40 + cc4) = curv;
            __syncthreads();
            int k = kc >> 3, n0 = (kc & 7) << 5;
            int kh = k / 3, kw = k - kh * 3;
            bf16x8 bfr = *(const bf16x8*)(chunk + (wn * 16 + l16) * 40 + lg * 8);
            #pragma unroll
            for (int mt = 0; mt < 2; ++mt) {
                int px = wm * 32 + mt * 16 + l16;
                bf16x8 afr = *(const bf16x8*)(xs + (kh * 66 + px + kw) * 264 + n0 + lg * 8);
                acc[mt] = __builtin_amdgcn_mfma_f32_16x16x32_bf16(afr, bfr, acc[mt], 0, 0, 0);
            }
            __syncthreads();
        }
        int cm = wn * 16 + l16;
        float bias = b_d1[cm];
        #pragma unroll
        for (int mt = 0; mt < 2; ++mt)
            #pragma unroll
            for (int r = 0; r < 4; ++r) {
                int px = wm * 32 + mt * 16 + lg * 4 + r;
                float v = acc[mt][r] + bias;
                ydl[px * 68 + cm] = v > 0.f ? v : 0.f;
            }
    }
    __syncthreads();

    // ---- d[px][9] = yd . w_d2^T + b_d2 ; ekT[k][p] = exp(-2d)
    for (int t = tid; t < 576; t += 512) {
        int px = t / 9, k = t - px * 9;
        float sum = b_d2[k];
        const float* yr = ydl + px * 68;
        const float* wr = w_d2 + k * 64;
        #pragma unroll 8
        for (int m = 0; m < 64; ++m) sum += yr[m] * wr[m];
        ekT[(size_t)k * PTOT + p0 + px] = exp2f(NEXP2 * sum);
    }
}

// ---------------- final kernel: out = (patches*attn) . W ----------------
#define FN_EK 104544                  // [9][64] f32 = 2304
#define FN_W  (FN_EK + 2304)          // [256][40] bf16 = 20480
#define FN_Z  (FN_W + 20480)          // [64][40] bf16 = 5120
#define FN_TOTAL (FN_Z + 5120)        // 132448 B

__global__ __launch_bounds__(512, 1) void k_final(const float* __restrict__ x,
        const short* __restrict__ Wr, const short* __restrict__ en, const float* __restrict__ ekT,
        float* __restrict__ out) {
    extern __shared__ char smem[];
    short* xs  = (short*)(smem);
    float* ekl = (float*)(smem + FN_EK);
    short* wch = (short*)(smem + FN_W);
    short* zl  = (short*)(smem + FN_Z);
    float* ot  = (float*)(smem);  // epilogue reuse (69632 B < 104544)

    const int rw = blockIdx.x;
    const int b = rw >> 6, h = rw & 63;
    const int p0 = rw << 6;
    const int tid = threadIdx.x;
    const int lane = tid & 63, wave = tid >> 6;
    const int l16 = lane & 15, lg = lane >> 4;
    const int wn = wave & 3, wm = wave >> 2;

    stage_xs(xs, x, b, h, 2.0f);  // x pre-scaled by 2: folds attn = 2/(1+q)
    for (int i = tid; i < 576; i += 512) {
        int k = i >> 6, px = i & 63;
        ekl[i] = ekT[(size_t)k * PTOT + p0 + px];
    }
    __syncthreads();

    const int wrow = tid >> 1, whalf = tid & 1;       // W-chunk staging map
    const int zpx = tid >> 3, zn4 = (tid & 7) << 2;   // z-tile map

    bf16x8 wpref0, wpref1;
    bf16x4 enpref;
    {
        const short* src = Wr + (size_t)wrow * 2304 + whalf * 16;
        wpref0 = *(const bf16x8*)(src);
        wpref1 = *(const bf16x8*)(src + 8);
        enpref = *(const bf16x4*)(en + (size_t)(p0 + zpx) * 256 + zn4);
    }

    f32x4 acc[2][4] = {};

    for (int kc = 0; kc < 72; ++kc) {
        const int k = kc >> 3, n0 = (kc & 7) << 5;
        const int kh = k / 3, kw = k - kh * 3;
        bf16x8 w0 = wpref0, w1 = wpref1;
        bf16x4 e4 = enpref;
        if (kc < 71) {  // prefetch next chunk (stays in flight over this step's MFMA)
            const short* src = Wr + (size_t)wrow * 2304 + (kc + 1) * 32 + whalf * 16;
            wpref0 = *(const bf16x8*)(src);
            wpref1 = *(const bf16x8*)(src + 8);
            int n0n = ((kc + 1) & 7) << 5;
            enpref = *(const bf16x4*)(en + (size_t)(p0 + zpx) * 256 + n0n + zn4);
        }
        // write W chunk [256][40]
        *(bf16x8*)(wch + wrow * 40 + whalf * 16)     = w0;
        *(bf16x8*)(wch + wrow * 40 + whalf * 16 + 8) = w1;
        // cooperative z tile: z[px][n'] = 2*x_patch * rcp(1 + ek*en)
        {
            float ekv = ekl[k * 64 + zpx];
            bf16x4 x4 = *(const bf16x4*)(xs + (kh * 66 + zpx + kw) * 264 + n0 + zn4);
            bf16x4 zz;
            #pragma unroll
            for (int i = 0; i < 4; ++i) {
                float q = 1.0f + ekv * bf2f(e4[i]);
                float att = __builtin_amdgcn_rcpf(q);
                zz[i] = f2bf(bf2f(x4[i]) * att);
            }
            *(bf16x4*)(zl + zpx * 40 + zn4) = zz;
        }
        __syncthreads();
        // MFMA: wave = 64px x 64o slice
        bf16x8 afr[2], bfr[4];
        #pragma unroll
        for (int mt = 0; mt < 2; ++mt)
            afr[mt] = *(const bf16x8*)(zl + (wm * 32 + mt * 16 + l16) * 40 + lg * 8);
        #pragma unroll
        for (int nt = 0; nt < 4; ++nt)
            bfr[nt] = *(const bf16x8*)(wch + (wn * 64 + nt * 16 + l16) * 40 + lg * 8);
        #pragma unroll
        for (int mt = 0; mt < 2; ++mt)
            #pragma unroll
            for (int nt = 0; nt < 4; ++nt)
                acc[mt][nt] = __builtin_amdgcn_mfma_f32_16x16x32_bf16(afr[mt], bfr[nt], acc[mt][nt], 0, 0, 0);
        __syncthreads();
    }

    // epilogue: acc -> LDS [256 o][68] f32, then coalesced f32x4 stores
    #pragma unroll
    for (int nt = 0; nt < 4; ++nt) {
        int o = wn * 64 + nt * 16 + l16;
        #pragma unroll
        for (int mt = 0; mt < 2; ++mt)
            #pragma unroll
            for (int r = 0; r < 4; ++r) {
                int px = wm * 32 + mt * 16 + lg * 4 + r;
                ot[o * 68 + px] = acc[mt][nt][r];
            }
    }
    __syncthreads();
    {
        int o = tid >> 1, seg = tid & 1;
        float* dst = out + (((size_t)b * 256 + o) * 64 + h) * 64 + seg * 32;
        const float* srcp = ot + o * 68 + seg * 32;
        #pragma unroll
        for (int j = 0; j < 8; ++j)
            *(f32x4*)(dst + 4 * j) = *(const f32x4*)(srcp + 4 * j);
    }
}

// ---------------- launcher ----------------
extern "C" void kernel_launch(void* const* d_in, const int* in_sizes, int n_in,
                              void* d_out, int out_size, void* d_ws, size_t ws_size,
                              hipStream_t stream) {
    const float* x    = (const float*)d_in[0];
    const float* w_c1 = (const float*)d_in[1];
    const float* b_c1 = (const float*)d_in[2];
    const float* w_c2 = (const float*)d_in[3];
    const float* b_c2 = (const float*)d_in[4];
    const float* w_d1 = (const float*)d_in[5];
    const float* b_d1 = (const float*)d_in[6];
    const float* w_d2 = (const float*)d_in[7];
    const float* b_d2 = (const float*)d_in[8];
    const float* Wt   = (const float*)d_in[9];
    float* out = (float*)d_out;
    char* ws = (char*)d_ws;

    short* wc1b = (short*)(ws + WS_WC1B);
    short* wc2b = (short*)(ws + WS_WC2B);
    short* wd1r = (short*)(ws + WS_WD1R);
    short* Wr   = (short*)(ws + WS_WR);
    float* ekT  = (float*)(ws + WS_EKT);
    short* en   = (short*)(ws + WS_EN);

    hipFuncSetAttribute((const void*)k_branch, hipFuncAttributeMaxDynamicSharedMemorySize, BR_TOTAL);
    hipFuncSetAttribute((const void*)k_final,  hipFuncAttributeMaxDynamicSharedMemorySize, FN_TOTAL);

    k_prep<<<3008, 256, 0, stream>>>(Wt, w_d1, w_c1, w_c2, Wr, wd1r, wc1b, wc2b);
    k_branch<<<512, 512, BR_TOTAL, stream>>>(x, b_c1, b_c2, b_d1, w_d2, b_d2, wc1b, wc2b, wd1r, en, ekT);
    k_final<<<512, 512, FN_TOTAL, stream>>>(x, Wr, en, ekT, out);
}